// Round 1
// baseline (463.133 us; speedup 1.0000x reference)
//
#include <hip/hip_runtime.h>
#include <math.h>

#define SB 8
#define SS 2048
#define SH 768
#define ALPHA 0.5f

// ws float layout:
// 0                : rnk  [SB*SS]  (16384)
// 16384            : ksum [SB*SH]  (6144)
// 22528            : Nk   [8]
// 22536            : qsum [8]
// 22544            : acc  [8]

__global__ __launch_bounds__(256) void knorm_kernel(const float* __restrict__ K,
                                                    float* __restrict__ rnk) {
  int lane = threadIdx.x & 63;
  int r = blockIdx.x * 4 + (threadIdx.x >> 6);
  const float4* rv = (const float4*)(K + (size_t)r * SH);
  float4 a = rv[lane], b = rv[lane + 64], c = rv[lane + 128];
  float s = a.x*a.x + a.y*a.y + a.z*a.z + a.w*a.w
          + b.x*b.x + b.y*b.y + b.z*b.z + b.w*b.w
          + c.x*c.x + c.y*c.y + c.z*c.z + c.w*c.w;
  #pragma unroll
  for (int m = 1; m < 64; m <<= 1) s += __shfl_xor(s, m, 64);
  if (lane == 0) rnk[r] = 1.0f / fmaxf(sqrtf(s), 1e-12f);
}

__global__ __launch_bounds__(256) void mask_sums(const float* __restrict__ qm,
                                                 const float* __restrict__ km,
                                                 float* __restrict__ Nk,
                                                 float* __restrict__ qsum) {
  __shared__ float sq[256], sk[256];
  int b = blockIdx.x, t = threadIdx.x;
  float aq = 0.f, ak = 0.f;
  for (int j = t; j < SS; j += 256) { aq += qm[b * SS + j]; ak += km[b * SS + j]; }
  sq[t] = aq; sk[t] = ak; __syncthreads();
  for (int off = 128; off > 0; off >>= 1) {
    if (t < off) { sq[t] += sq[t + off]; sk[t] += sk[t + off]; }
    __syncthreads();
  }
  if (t == 0) { qsum[b] = sq[0]; Nk[b] = sk[0]; }
}

__global__ __launch_bounds__(256) void ksum_kernel(const float* __restrict__ K,
                                                   const float* __restrict__ km,
                                                   const float* __restrict__ rnk,
                                                   float* __restrict__ ksum) {
  int b = blockIdx.y, jc = blockIdx.x, t = threadIdx.x;
  __shared__ float w[64];
  int j0 = jc * 64;
  if (t < 64) {
    int j = j0 + t;
    w[t] = km[b * SS + j] * rnk[b * SS + j];
  }
  __syncthreads();
  float a0 = 0.f, a1 = 0.f, a2 = 0.f;
  const float* base = K + ((size_t)b * SS + j0) * SH;
  for (int jj = 0; jj < 64; jj++) {
    float wv = w[jj];
    if (wv != 0.0f) {
      const float* rp = base + (size_t)jj * SH;
      a0 += rp[t] * wv;
      a1 += rp[t + 256] * wv;
      a2 += rp[t + 512] * wv;
    }
  }
  atomicAdd(&ksum[b * SH + t], a0);
  atomicAdd(&ksum[b * SH + t + 256], a1);
  atomicAdd(&ksum[b * SH + t + 512], a2);
}

__global__ __launch_bounds__(256) void band_kernel(
    const float* __restrict__ Q, const float* __restrict__ K,
    const float* __restrict__ qmask, const float* __restrict__ kmask,
    const float* __restrict__ temp, const float* __restrict__ rnk,
    const float* __restrict__ ksum, const float* __restrict__ Nk,
    float* __restrict__ acc) {
  __shared__ float tab[64];
  __shared__ float scs[4];
  int tid = threadIdx.x;
  if (tid < 64) {
    float invt = 1.0f / temp[0];
    tab[tid] = expf(-ALPHA * fabsf((float)(tid - 31))) * invt;
  }
  __syncthreads();
  int w = tid >> 6, lane = tid & 63;
  int g = lane >> 4, u = lane & 15;
  int r = blockIdx.x * 4 + w;
  int b = r >> 11, i = r & (SS - 1);
  float qm = qmask[r];
  float score = 0.0f;
  if (qm != 0.0f) {
    const float4* qr = (const float4*)(Q + (size_t)r * SH);
    float4 qv[12];
    float nn = 0.f;
    #pragma unroll
    for (int m = 0; m < 12; m++) {
      qv[m] = qr[u + 16 * m];
      nn += qv[m].x*qv[m].x + qv[m].y*qv[m].y + qv[m].z*qv[m].z + qv[m].w*qv[m].w;
    }
    nn += __shfl_xor(nn, 1, 64); nn += __shfl_xor(nn, 2, 64);
    nn += __shfl_xor(nn, 4, 64); nn += __shfl_xor(nn, 8, 64);
    float rn = 1.0f / fmaxf(sqrtf(nn), 1e-12f);
    #pragma unroll
    for (int m = 0; m < 12; m++) {
      qv[m].x *= rn; qv[m].y *= rn; qv[m].z *= rn; qv[m].w *= rn;
    }
    // q_hat . ksum  (covers ALL valid j as exp(l)~1 far field)
    const float4* ks = (const float4*)(ksum + (size_t)b * SH);
    float d0 = 0.f;
    #pragma unroll
    for (int m = 0; m < 12; m++) {
      float4 kv = ks[u + 16 * m];
      d0 += qv[m].x*kv.x + qv[m].y*kv.y + qv[m].z*kv.z + qv[m].w*kv.w;
    }
    d0 += __shfl_xor(d0, 1, 64); d0 += __shfl_xor(d0, 2, 64);
    d0 += __shfl_xor(d0, 4, 64); d0 += __shfl_xor(d0, 8, 64);

    float a_num = 0.f, a_den = 0.f;
    const float* kmrow = kmask + (size_t)b * SS;
    const float* rnkrow = rnk + (size_t)b * SS;
    const float* Kb = K + (size_t)b * SS * SH;
    // band: j in [i-31, i+32]; quarter-group g handles t = tt+g
    for (int tt = 0; tt < 64; tt += 4) {
      int t = tt + g;
      int j = i - 31 + t;
      int jc = j < 0 ? 0 : (j >= SS ? SS - 1 : j);
      float wf = 0.f;
      if (j >= 0 && j < SS) wf = kmrow[j] * rnkrow[j];
      const float4* kr = (const float4*)(Kb + (size_t)jc * SH);
      float d = 0.f;
      #pragma unroll
      for (int m = 0; m < 12; m++) {
        float4 kv = kr[u + 16 * m];
        d += qv[m].x*kv.x + qv[m].y*kv.y + qv[m].z*kv.z + qv[m].w*kv.w;
      }
      d += __shfl_xor(d, 1, 64); d += __shfl_xor(d, 2, 64);
      d += __shfl_xor(d, 4, 64); d += __shfl_xor(d, 8, 64);
      float sv = d * wf;           // s_ij (0 if invalid/out of range)
      float lv = sv * tab[t];      // s * decay / temp
      float ev = expm1f(lv);       // exp(l) - 1  (exactly 0 when invalid)
      a_num += ev * sv;
      a_den += ev;
    }
    a_num += __shfl_xor(a_num, 16, 64); a_num += __shfl_xor(a_num, 32, 64);
    a_den += __shfl_xor(a_den, 16, 64); a_den += __shfl_xor(a_den, 32, 64);
    score = qm * (d0 + a_num) / (Nk[b] + a_den);
  }
  if (lane == 0) scs[w] = score;
  __syncthreads();
  if (tid == 0) atomicAdd(&acc[b], scs[0] + scs[1] + scs[2] + scs[3]);
}

__global__ void finalize_kernel(const float* __restrict__ acc,
                                const float* __restrict__ qsum,
                                float* __restrict__ out) {
  int b = threadIdx.x;
  if (b < SB) out[b] = acc[b] / fmaxf(qsum[b], 1.0f);
}

extern "C" void kernel_launch(void* const* d_in, const int* in_sizes, int n_in,
                              void* d_out, int out_size, void* d_ws, size_t ws_size,
                              hipStream_t stream) {
  const float* Q    = (const float*)d_in[0];
  const float* K    = (const float*)d_in[1];
  const float* qm   = (const float*)d_in[2];
  const float* km   = (const float*)d_in[3];
  const float* temp = (const float*)d_in[4];
  float* ws   = (float*)d_ws;
  float* rnk  = ws;
  float* ksum = ws + SB * SS;
  float* Nk   = ksum + SB * SH;
  float* qsum = Nk + 8;
  float* acc  = qsum + 8;
  float* outp = (float*)d_out;

  // zero ksum + Nk + qsum + acc (atomically accumulated / read-before-full-write)
  hipMemsetAsync(ksum, 0, (SB * SH + 24) * sizeof(float), stream);

  knorm_kernel<<<SB * SS / 4, 256, 0, stream>>>(K, rnk);
  mask_sums<<<SB, 256, 0, stream>>>(qm, km, Nk, qsum);
  ksum_kernel<<<dim3(32, SB), 256, 0, stream>>>(K, km, rnk, ksum);
  band_kernel<<<SB * SS / 4, 256, 0, stream>>>(Q, K, qm, km, temp, rnk, ksum, Nk, acc);
  finalize_kernel<<<1, 64, 0, stream>>>(acc, qsum, outp);
}